// Round 2
// baseline (451.592 us; speedup 1.0000x reference)
//
#include <hip/hip_runtime.h>

typedef short bf16x8 __attribute__((ext_vector_type(8)));
typedef float f32x4 __attribute__((ext_vector_type(4)));

#define HID   2048
#define S_LEN 2048
#define NH    16
#define HD    128
#define BATCH 2
#define NROWS (BATCH * S_LEN)  // 4096

__device__ __forceinline__ float bf2f(unsigned short u) {
    union { unsigned int i; float f; } v;
    v.i = ((unsigned int)u) << 16;
    return v.f;
}
__device__ __forceinline__ unsigned short f2bf(float f) {
    union { float f; unsigned int i; } v;
    v.f = f;
    unsigned int u = v.i;
    return (unsigned short)((u + 0x7fffu + ((u >> 16) & 1u)) >> 16);
}

// packed f32x2 -> bf16x2 (RNE). Prefer HW v_cvt_pk_bf16_f32 on gfx950.
__device__ __forceinline__ unsigned int pkbf(float a, float b) {
#if defined(__has_builtin) && __has_builtin(__builtin_amdgcn_cvt_pk_bf16_f32)
    typedef __bf16 bf2_t __attribute__((ext_vector_type(2)));
    bf2_t v = __builtin_amdgcn_cvt_pk_bf16_f32(a, b);
    unsigned int u;
    __builtin_memcpy(&u, &v, 4);
    return u;
#else
    return (unsigned int)f2bf(a) | ((unsigned int)f2bf(b) << 16);
#endif
}

__device__ __forceinline__ float exp2_fast(float x) {
#if defined(__has_builtin) && __has_builtin(__builtin_amdgcn_exp2f)
    return __builtin_amdgcn_exp2f(x);
#else
    return __expf(x * 0.6931471805599453f);
#endif
}

// async global->LDS, 16B per lane. LDS dest = wave-uniform base + lane*16B.
__device__ __forceinline__ void async16(const unsigned short* g, unsigned short* l) {
    __builtin_amdgcn_global_load_lds(
        (const __attribute__((address_space(1))) unsigned int*)g,
        (__attribute__((address_space(3))) unsigned int*)l, 16, 0, 0);
}

// ---------------- prep: z<3 -> transpose+cast W_z; z==3 -> cast hs -> bf16 ----------------
__global__ __launch_bounds__(256) void prep(const float* __restrict__ hs,
                                            const float* __restrict__ Wa,
                                            const float* __restrict__ Wb,
                                            const float* __restrict__ Wc,
                                            unsigned short* __restrict__ Xb,
                                            unsigned short* __restrict__ WT) {
    int z = blockIdx.z;
    int t = threadIdx.x;
    if (z == 3) {
        size_t idx = (((size_t)blockIdx.y * 64 + blockIdx.x) * 256 + t) * 8;
        float4 v0 = *(const float4*)(hs + idx);
        float4 v1 = *(const float4*)(hs + idx + 4);
        uint4 o;
        o.x = pkbf(v0.x, v0.y);
        o.y = pkbf(v0.z, v0.w);
        o.z = pkbf(v1.x, v1.y);
        o.w = pkbf(v1.z, v1.w);
        *(uint4*)(Xb + idx) = o;
        return;
    }
    __shared__ float tile[32][33];
    int tx = t & 31, ty = t >> 5;  // 32 x 8
    int bx = blockIdx.x, by = blockIdx.y;
    const float* W = (z == 0) ? Wa : ((z == 1) ? Wb : Wc);
    unsigned short* dst = WT + (size_t)z * HID * HID;
#pragma unroll
    for (int i = 0; i < 4; i++)
        tile[ty + i * 8][tx] = W[(size_t)(by * 32 + ty + i * 8) * HID + bx * 32 + tx];
    __syncthreads();
#pragma unroll
    for (int i = 0; i < 4; i++)
        dst[(size_t)(bx * 32 + ty + i * 8) * HID + by * 32 + tx] = f2bf(tile[tx][ty + i * 8]);
}

// ---------------- standalone transpose + cast (used for Wo) ----------------
__global__ __launch_bounds__(256) void transpose_cast(const float* __restrict__ W,
                                                      unsigned short* __restrict__ WT) {
    __shared__ float tile[32][33];
    int t = threadIdx.x;
    int tx = t & 31, ty = t >> 5;
    int bx = blockIdx.x, by = blockIdx.y;
#pragma unroll
    for (int i = 0; i < 4; i++)
        tile[ty + i * 8][tx] = W[(size_t)(by * 32 + ty + i * 8) * HID + bx * 32 + tx];
    __syncthreads();
#pragma unroll
    for (int i = 0; i < 4; i++)
        WT[(size_t)(bx * 32 + ty + i * 8) * HID + by * 32 + tx] = f2bf(tile[tx][ty + i * 8]);
}

// ===========================================================================
// 256x256-tile QKV GEMM, T3+T4+T5 phase pipeline (BK=32, ring-4 LDS buffers),
// fused RoPE / V^T epilogue.
//
// Schedule (per K-tile kt, 2 phases; 64 K-tiles of BK=32):
//  P0: issue stage A(kt+2) -> slot (kt+2)&3 (free: last read was kt-2)
//      ds_read af[0..3] + bfr[0..3] from slot kt&3; s_barrier;
//      setprio(1); 16 MFMA (mt0-3 x nt0-3); setprio(0); s_barrier
//  P1: issue stage B(kt+2); ds_read af[4..7];
//      s_waitcnt vmcnt(4)   <- kt+1 fully landed, kt+2's 4 loads stay in flight
//      s_barrier; setprio(1); 16 MFMA (mt4-7 x nt0-3); setprio(0); s_barrier
// vmcnt is NEVER drained to 0 in the loop (T4). Ring-4 makes stage targets
// race-free by construction. LDS rows are 64B, 16B chunks XOR-swizzled with
// (row&3); DMA dest is linear, global source is pre-swizzled (rule 21).
// Tail: ktn clamps to 63 -> re-issues tile 63's own data (identical bytes,
// benign) which PRESERVES the vmcnt in-flight count invariant.
// ===========================================================================
__global__ __launch_bounds__(512, 2) void gemm256(const unsigned short* __restrict__ A,
                                                  const unsigned short* __restrict__ Bt,
                                                  unsigned short* __restrict__ Qo,
                                                  unsigned short* __restrict__ Ko,
                                                  unsigned short* __restrict__ Vo,
                                                  const float* __restrict__ cosp,
                                                  const float* __restrict__ sinp) {
    // 4 ring slots x (A[256][32] + B[256][32]) shorts = 4 x 32KB = 128 KB.
    // Reused by the RoPE epilogue as 32 x 2048-short swap slots (exact fit).
    __shared__ unsigned short SM[65536];
    int t = threadIdx.x;
    int wave = t >> 6, lane = t & 63;
    int wm = wave >> 2, wn = wave & 3;        // 2 x 4 waves
    int c = lane & 15, quad = lane >> 4;
    int m0 = blockIdx.y * 256, n0 = blockIdx.x * 256;

    // staging: thread covers LDS row lr (issue j=0) / lr+128 (j=1), chunk lane&3.
    // LDS[row][pos] holds global chunk (pos ^ (row&3)); row&3 == (lane>>2)&3.
    int lr = wave * 16 + (lane >> 2);
    int scw = ((lane & 3) ^ ((lane >> 2) & 3)) * 8;
    const unsigned short* Ag = A + (size_t)(m0 + lr) * HID + scw;
    const unsigned short* Bg = Bt + (size_t)(n0 + lr) * HID + scw;

    f32x4 zero = {0.f, 0.f, 0.f, 0.f};
    f32x4 acc[8][4];
#pragma unroll
    for (int i = 0; i < 8; i++)
#pragma unroll
        for (int j = 0; j < 4; j++) acc[i][j] = zero;

    // prologue: stage kt0 and kt1 (8 issues), land kt0, one aligning barrier.
#pragma unroll
    for (int kt = 0; kt < 2; kt++) {
        unsigned short* Sl = SM + kt * 16384;
        async16(Ag + kt * 32, Sl + wave * 512);
        async16(Ag + kt * 32 + 128 * HID, Sl + wave * 512 + 4096);
        async16(Bg + kt * 32, Sl + 8192 + wave * 512);
        async16(Bg + kt * 32 + 128 * HID, Sl + 8192 + wave * 512 + 4096);
    }
    __builtin_amdgcn_s_waitcnt(0x0F74);  // vmcnt(4): kt0's A+B landed
    __builtin_amdgcn_s_barrier();

    int cxor = (quad ^ (c & 3)) * 8;  // swizzled chunk offset for frag reads

#pragma unroll 4
    for (int kt = 0; kt < 64; kt++) {
        const unsigned short* Sa = SM + (kt & 3) * 16384;
        const unsigned short* Sb = Sa + 8192;
        int ktn = (kt + 2 > 63) ? 63 : kt + 2;  // clamp: dup re-issue is benign
        unsigned short* Sn = SM + (ktn & 3) * 16384;

        // ---- phase 0 ----
        async16(Ag + ktn * 32, Sn + wave * 512);
        async16(Ag + ktn * 32 + 128 * HID, Sn + wave * 512 + 4096);
        bf16x8 af[4], bfr[4];
#pragma unroll
        for (int mt = 0; mt < 4; mt++)
            af[mt] = *(const bf16x8*)(Sa + (wm * 128 + mt * 16 + c) * 32 + cxor);
#pragma unroll
        for (int nt = 0; nt < 4; nt++)
            bfr[nt] = *(const bf16x8*)(Sb + (wn * 64 + nt * 16 + c) * 32 + cxor);
        __builtin_amdgcn_s_barrier();
        __builtin_amdgcn_s_setprio(1);
#pragma unroll
        for (int mt = 0; mt < 4; mt++)
#pragma unroll
            for (int nt = 0; nt < 4; nt++)
                acc[mt][nt] = __builtin_amdgcn_mfma_f32_16x16x32_bf16(af[mt], bfr[nt],
                                                                      acc[mt][nt], 0, 0, 0);
        __builtin_amdgcn_s_setprio(0);
        __builtin_amdgcn_s_barrier();

        // ---- phase 1 ----
        async16(Bg + ktn * 32, Sn + 8192 + wave * 512);
        async16(Bg + ktn * 32 + 128 * HID, Sn + 8192 + wave * 512 + 4096);
#pragma unroll
        for (int mt = 0; mt < 4; mt++)
            af[mt] = *(const bf16x8*)(Sa + (wm * 128 + (mt + 4) * 16 + c) * 32 + cxor);
        __builtin_amdgcn_s_waitcnt(0x0F74);  // vmcnt(4): kt+1 resident after barrier
        __builtin_amdgcn_s_barrier();
        __builtin_amdgcn_s_setprio(1);
#pragma unroll
        for (int mt = 0; mt < 4; mt++)
#pragma unroll
            for (int nt = 0; nt < 4; nt++)
                acc[mt + 4][nt] = __builtin_amdgcn_mfma_f32_16x16x32_bf16(af[mt], bfr[nt],
                                                                          acc[mt + 4][nt], 0, 0, 0);
        __builtin_amdgcn_s_setprio(0);
        __builtin_amdgcn_s_barrier();
    }

    __syncthreads();  // full drain (incl. leftover DMA) before SM reuse

    int mat = n0 >> 11;                 // block-uniform: 0=Q, 1=K, 2=V
    int hbase = (n0 & 2047) >> 7;       // = (bx&7)*2; tile spans 2 heads
    int h = hbase + (wn >> 1);
    if (mat == 2) {
        // V^T: [b][h][d][s], 4 consecutive s per lane -> packed 8B store
#pragma unroll
        for (int mt = 0; mt < 8; mt++)
#pragma unroll
            for (int nt = 0; nt < 4; nt++) {
                int d = (wn & 1) * 64 + nt * 16 + c;
                int row0 = m0 + wm * 128 + mt * 16 + quad * 4;
                int b = row0 >> 11, s = row0 & 2047;
                ushort4 o;
                o.x = f2bf(acc[mt][nt][0]);
                o.y = f2bf(acc[mt][nt][1]);
                o.z = f2bf(acc[mt][nt][2]);
                o.w = f2bf(acc[mt][nt][3]);
                *(ushort4*)(Vo + ((size_t)(b * NH + h) * HD + d) * S_LEN + s) = o;
            }
    } else {
        // Q/K with fused RoPE. Pair (d, d+64) lives in wave^1 at the same lane
        // and (mt,nt,r). Swap via SM (exact 32 x 2048-short fit, conflict-free).
        unsigned short* Cb = (mat == 0) ? Qo : Ko;
        float scl = (mat == 0) ? 0.12751743f : 1.0f;  // log2(e)/sqrt(128) folded into Q
#pragma unroll
        for (int mt = 0; mt < 8; mt++)
#pragma unroll
            for (int nt = 0; nt < 4; nt++) {
                ushort4 o;
                o.x = f2bf(acc[mt][nt][0]);
                o.y = f2bf(acc[mt][nt][1]);
                o.z = f2bf(acc[mt][nt][2]);
                o.w = f2bf(acc[mt][nt][3]);
                *(ushort4*)(SM + (mt * 4 + nt) * 2048 + t * 4) = o;
            }
        __syncthreads();
        int partner = (wave ^ 1) * 64 + lane;
        float sgn = (wn & 1) ? 1.0f : -1.0f;
#pragma unroll
        for (int mt = 0; mt < 8; mt++) {
#pragma unroll
            for (int nt = 0; nt < 4; nt++) {
                ushort4 pv = *(const ushort4*)(SM + (mt * 4 + nt) * 2048 + partner * 4);
                float part[4] = {bf2f(pv.x), bf2f(pv.y), bf2f(pv.z), bf2f(pv.w)};
                int d = (wn & 1) * 64 + nt * 16 + c;
#pragma unroll
                for (int r = 0; r < 4; r++) {
                    int row = m0 + wm * 128 + mt * 16 + quad * 4 + r;
                    int b = row >> 11, s = row & 2047;
                    float cv = cosp[s * HD + d], sv = sinp[s * HD + d];
                    float out = (acc[mt][nt][r] * cv + sgn * part[r] * sv) * scl;
                    Cb[((size_t)(b * NH + h) * S_LEN + s) * HD + d] = f2bf(out);
                }
            }
        }
    }
}

// ---------------- bf16 GEMM, BK=64 XOR-swizzled staging (legacy 128^2) ----------------
// Kept for the fallback path and for the output GEMM (MODE 2: 512 blocks = one
// full 2-block/CU wave; a 256^2 version would idle half the CUs).
template <int MODE>
__global__ __launch_bounds__(256, 2) void gemm_bt(const unsigned short* __restrict__ A,
                                                  const unsigned short* __restrict__ Bt,
                                                  unsigned short* __restrict__ Qo,
                                                  unsigned short* __restrict__ Ko,
                                                  unsigned short* __restrict__ Vo,
                                                  float* __restrict__ Fo,
                                                  const float* __restrict__ cosp,
                                                  const float* __restrict__ sinp,
                                                  int n_shift) {
    __shared__ unsigned short SM[16384];       // 32 KB: Asm(16K) + Bsm(16K); reused for rope swap
    unsigned short* Asm = SM;                  // 128 rows x 64 shorts, XOR-swizzled cols
    unsigned short* Bsm = SM + 8192;
    int t = threadIdx.x;
    int wave = t >> 6, lane = t & 63;
    int wm = wave >> 1, wn = wave & 1;
    int c = lane & 15, quad = lane >> 4;
    int m0 = blockIdx.y * 128, nloc = blockIdx.x * 128;

    int lr = lane >> 3;
    int cb = (lane & 7) ^ (lr & 7);
    const unsigned short* Ag = A + (size_t)(m0 + wave * 32 + lr) * HID + cb * 8;
    const unsigned short* Bg = Bt + (size_t)(nloc + wave * 32 + lr) * HID + cb * 8;
    unsigned short* Al = Asm + wave * 2048;  // 32 rows * 64 shorts
    unsigned short* Bl = Bsm + wave * 2048;

    f32x4 zero = {0.f, 0.f, 0.f, 0.f};
    f32x4 acc[4][4];
#pragma unroll
    for (int i = 0; i < 4; i++)
#pragma unroll
        for (int j = 0; j < 4; j++) acc[i][j] = zero;

    for (int it = 0; it < 32; it++) {
        int k0 = it * 64;
#pragma unroll
        for (int j = 0; j < 4; j++) {
            async16(Ag + k0 + j * 8 * HID, Al + j * 512);
            async16(Bg + k0 + j * 8 * HID, Bl + j * 512);
        }
        __syncthreads();
#pragma unroll
        for (int kk = 0; kk < 2; kk++) {
            bf16x8 af[4], bfr[4];
#pragma unroll
            for (int mt = 0; mt < 4; mt++)
                af[mt] = *(const bf16x8*)(Asm + (wm * 64 + mt * 16 + c) * 64 +
                                          (((kk * 4 + quad) ^ (c & 7)) * 8));
#pragma unroll
            for (int nt = 0; nt < 4; nt++)
                bfr[nt] = *(const bf16x8*)(Bsm + (wn * 64 + nt * 16 + c) * 64 +
                                           (((kk * 4 + quad) ^ (c & 7)) * 8));
#pragma unroll
            for (int mt = 0; mt < 4; mt++)
#pragma unroll
                for (int nt = 0; nt < 4; nt++)
                    acc[mt][nt] = __builtin_amdgcn_mfma_f32_16x16x32_bf16(af[mt], bfr[nt],
                                                                          acc[mt][nt], 0, 0, 0);
        }
        __syncthreads();
    }

    if (MODE == 2) {
#pragma unroll
        for (int mt = 0; mt < 4; mt++)
#pragma unroll
            for (int nt = 0; nt < 4; nt++)
#pragma unroll
                for (int r = 0; r < 4; r++) {
                    int row = m0 + wm * 64 + mt * 16 + quad * 4 + r;
                    int col = nloc + wn * 64 + nt * 16 + c;
                    Fo[(size_t)row * HID + col] = acc[mt][nt][r];
                }
    } else {
        int nglob0 = n_shift + nloc;
        int mat = nglob0 >> 11;         // block-uniform
        int h = (nglob0 & 2047) >> 7;   // block covers exactly one head (128 cols)
        if (mat == 2) {
#pragma unroll
            for (int mt = 0; mt < 4; mt++)
#pragma unroll
                for (int nt = 0; nt < 4; nt++) {
                    int d = wn * 64 + nt * 16 + c;
                    int row0 = m0 + wm * 64 + mt * 16 + quad * 4;
                    int b = row0 >> 11, s = row0 & 2047;
                    ushort4 o;
                    o.x = f2bf(acc[mt][nt][0]);
                    o.y = f2bf(acc[mt][nt][1]);
                    o.z = f2bf(acc[mt][nt][2]);
                    o.w = f2bf(acc[mt][nt][3]);
                    *(ushort4*)(Vo + ((size_t)(b * NH + h) * HD + d) * S_LEN + s) = o;
                }
        } else {
            unsigned short* Cb = (mat == 0) ? Qo : Ko;
            float scl = (mat == 0) ? 0.12751743f : 1.0f;
            __syncthreads();
#pragma unroll
            for (int mt = 0; mt < 4; mt++)
#pragma unroll
                for (int nt = 0; nt < 4; nt++) {
                    ushort4 o;
                    o.x = f2bf(acc[mt][nt][0]);
                    o.y = f2bf(acc[mt][nt][1]);
                    o.z = f2bf(acc[mt][nt][2]);
                    o.w = f2bf(acc[mt][nt][3]);
                    *(ushort4*)(SM + (mt * 4 + nt) * 1024 + t * 4) = o;
                }
            __syncthreads();
            int partner = (wm * 2 + (wn ^ 1)) * 64 + lane;
            float sgn = wn ? 1.0f : -1.0f;
#pragma unroll
            for (int mt = 0; mt < 4; mt++) {
#pragma unroll
                for (int nt = 0; nt < 4; nt++) {
                    ushort4 pv = *(const ushort4*)(SM + (mt * 4 + nt) * 1024 + partner * 4);
                    float part[4] = {bf2f(pv.x), bf2f(pv.y), bf2f(pv.z), bf2f(pv.w)};
                    int col = wn * 64 + nt * 16 + c;
#pragma unroll
                    for (int r = 0; r < 4; r++) {
                        int row = m0 + wm * 64 + mt * 16 + quad * 4 + r;
                        int b = row >> 11, s = row & 2047;
                        float cv = cosp[s * HD + col], sv = sinp[s * HD + col];
                        float out = (acc[mt][nt][r] * cv + sgn * part[r] * sv) * scl;
                        Cb[((size_t)(b * NH + h) * S_LEN + s) * HD + col] = f2bf(out);
                    }
                }
            }
        }
    }
}

// ---------------- flash attention (no-max online softmax, S^T formulation) ----------------
#define PKS 72  // P row stride in shorts (144B = 9*16: b128-aligned, conflict-free)
__global__ __launch_bounds__(256, 2) void attn_kernel(const unsigned short* __restrict__ Q,
                                                      const unsigned short* __restrict__ Kg,
                                                      const unsigned short* __restrict__ Vt,
                                                      unsigned short* __restrict__ Aout) {
    __shared__ unsigned short Ksm[64 * 128];            // 16 KB, [key][d], XOR-swizzled chunks
    __shared__ unsigned short Vsm[128 * 64];            // 16 KB, [d][key], XOR-swizzled chunks
    __shared__ __align__(16) unsigned short Psm[4 * 2 * 16 * PKS];  // 18 KB
    int bh = blockIdx.y;
    int b = bh >> 4, h = bh & 15;
    int t = threadIdx.x;
    int wave = t >> 6, lane = t & 63;
    int c = lane & 15, quad = lane >> 4;
    int q0 = blockIdx.x * 128 + wave * 32;
    const unsigned short* Qp = Q + (size_t)bh * S_LEN * HD;
    const unsigned short* Kp = Kg + (size_t)bh * S_LEN * HD;
    const unsigned short* Vp = Vt + (size_t)bh * HD * S_LEN;

    bf16x8 qf[2][4];
#pragma unroll
    for (int qn = 0; qn < 2; qn++)
#pragma unroll
        for (int kk = 0; kk < 4; kk++)
            qf[qn][kk] = *(const bf16x8*)(Qp + (size_t)(q0 + qn * 16 + c) * HD + kk * 32 + quad * 8);

    f32x4 zero = {0.f, 0.f, 0.f, 0.f};
    f32x4 o_acc[2][8];
#pragma unroll
    for (int qn = 0; qn < 2; qn++)
#pragma unroll
        for (int nt = 0; nt < 8; nt++) o_acc[qn][nt] = zero;
    float lsum[2] = {0.f, 0.f};

    for (int key0 = 0; key0 < S_LEN; key0 += 64) {
#pragma unroll
        for (int j = 0; j < 4; j++) {
            int fc = (wave * 4 + j) * 64 + lane;
            int rK = fc >> 4, cbK = (fc & 15) ^ (rK & 15);
            async16(Kp + (size_t)(key0 + rK) * HD + cbK * 8, Ksm + (wave * 4 + j) * 512);
            int rV = fc >> 3, cbV = (fc & 7) ^ (rV & 7);
            async16(Vp + (size_t)rV * S_LEN + key0 + cbV * 8, Vsm + (wave * 4 + j) * 512);
        }
        __syncthreads();

        f32x4 sacc[4][2];
#pragma unroll
        for (int km = 0; km < 4; km++)
#pragma unroll
            for (int qn = 0; qn < 2; qn++) sacc[km][qn] = zero;
#pragma unroll
        for (int kk = 0; kk < 4; kk++) {
            bf16x8 kfr[4];
#pragma unroll
            for (int km = 0; km < 4; km++)
                kfr[km] = *(const bf16x8*)(Ksm + (km * 16 + c) * HD + (((kk * 4 + quad) ^ c)) * 8);
#pragma unroll
            for (int km = 0; km < 4; km++)
#pragma unroll
                for (int qn = 0; qn < 2; qn++)
                    sacc[km][qn] = __builtin_amdgcn_mfma_f32_16x16x32_bf16(kfr[km], qf[qn][kk],
                                                                           sacc[km][qn], 0, 0, 0);
        }

#pragma unroll
        for (int qn = 0; qn < 2; qn++) {
#pragma unroll
            for (int km = 0; km < 4; km++) {
                float e0 = exp2_fast(sacc[km][qn][0]);
                float e1 = exp2_fast(sacc[km][qn][1]);
                float e2 = exp2_fast(sacc[km][qn][2]);
                float e3 = exp2_fast(sacc[km][qn][3]);
                lsum[qn] += (e0 + e1) + (e2 + e3);
                uint2 pk;
                pk.x = pkbf(e0, e1);
                pk.y = pkbf(e2, e3);
                *(uint2*)(Psm + ((wave * 2 + qn) * 16 + c) * PKS + km * 16 + quad * 4) = pk;
            }
        }
        asm volatile("" ::: "memory");
        __builtin_amdgcn_s_waitcnt(0xc07f);  // lgkmcnt(0), vmcnt/expcnt unaffected
        asm volatile("" ::: "memory");

#pragma unroll
        for (int kf = 0; kf < 2; kf++) {
            bf16x8 pf[2];
#pragma unroll
            for (int qn = 0; qn < 2; qn++)
                pf[qn] = *(const bf16x8*)(Psm + ((wave * 2 + qn) * 16 + c) * PKS + kf * 32 + quad * 8);
#pragma unroll
            for (int nt = 0; nt < 8; nt++) {
                bf16x8 vf = *(const bf16x8*)(Vsm + (nt * 16 + c) * 64 +
                                             (((kf * 4 + quad) ^ (c & 7))) * 8);
#pragma unroll
                for (int qn = 0; qn < 2; qn++)
                    o_acc[qn][nt] = __builtin_amdgcn_mfma_f32_16x16x32_bf16(pf[qn], vf,
                                                                            o_acc[qn][nt], 0, 0, 0);
            }
        }
        __syncthreads();
    }

#pragma unroll
    for (int qn = 0; qn < 2; qn++) {
        lsum[qn] += __shfl_xor(lsum[qn], 16);
        lsum[qn] += __shfl_xor(lsum[qn], 32);
    }
    float inv[2][4];
#pragma unroll
    for (int qn = 0; qn < 2; qn++)
#pragma unroll
        for (int r = 0; r < 4; r++)
            inv[qn][r] = 1.0f / __shfl(lsum[qn], quad * 4 + r);

#pragma unroll
    for (int qn = 0; qn < 2; qn++) {
#pragma unroll
        for (int r = 0; r < 4; r++) {
            int srow = q0 + qn * 16 + quad * 4 + r;
            size_t base = ((size_t)(b * S_LEN + srow)) * HID + h * HD;
#pragma unroll
            for (int nt = 0; nt < 8; nt++)
                Aout[base + nt * 16 + c] = f2bf(o_acc[qn][nt][r] * inv[qn][r]);
        }
    }
}

extern "C" void kernel_launch(void* const* d_in, const int* in_sizes, int n_in,
                              void* d_out, int out_size, void* d_ws, size_t ws_size,
                              hipStream_t stream) {
    const float* hs   = (const float*)d_in[0];
    const float* cosp = (const float*)d_in[1];
    const float* sinp = (const float*)d_in[2];
    const float* Wq   = (const float*)d_in[3];
    const float* Wk   = (const float*)d_in[4];
    const float* Wv   = (const float*)d_in[5];
    const float* Wo   = (const float*)d_in[6];

    char* ws = (char*)d_ws;
    unsigned short* Xb = (unsigned short*)(ws);                      // 0-16 MB (reused as Aout)
    unsigned short* Qb = (unsigned short*)(ws + (16ull << 20));      // 16-32
    unsigned short* Kb = (unsigned short*)(ws + (32ull << 20));      // 32-48
    unsigned short* Vb = (unsigned short*)(ws + (48ull << 20));      // 48-64
    unsigned short* WT = (unsigned short*)(ws + (64ull << 20));      // 64-88 fused / 64-72 single

    const bool fused = ws_size >= (88ull << 20);

    if (fused) {
        // 1. cast + 3 weight transposes in one launch
        prep<<<dim3(64, 64, 4), 256, 0, stream>>>(hs, Wq, Wk, Wv, Xb, WT);
        // 2. fused QKV GEMM (256^2 tile, T3+T4+T5 pipeline) with RoPE epilogue
        gemm256<<<dim3(24, 16), 512, 0, stream>>>(Xb, WT, Qb, Kb, Vb, cosp, sinp);
        // 3. flash attention
        attn_kernel<<<dim3(16, 32), 256, 0, stream>>>(Qb, Kb, Vb, Xb /*Aout*/);
        // 4. Wo transpose into dead Qb region
        unsigned short* WoT = (unsigned short*)(ws + (16ull << 20));
        transpose_cast<<<dim3(64, 64), 256, 0, stream>>>(Wo, WoT);
        // 5. output GEMM, fp32 direct to d_out
        gemm_bt<2><<<dim3(16, 32), 256, 0, stream>>>(Xb, WoT, nullptr, nullptr, nullptr,
                                                     (float*)d_out, cosp, sinp, 0);
    } else {
        prep<<<dim3(64, 64, 1), 256, 0, stream>>>(hs, Wq, Wq, Wq, Xb, WT);
        prep<<<dim3(64, 64, 4), 256, 0, stream>>>(hs, Wq, Wq, Wq, Xb, WT);  // cast + Wq^T
        gemm_bt<0><<<dim3(16, 32), 256, 0, stream>>>(Xb, WT, Qb, Kb, Vb, nullptr,
                                                     cosp, sinp, 0);
        transpose_cast<<<dim3(64, 64), 256, 0, stream>>>(Wk, WT);
        gemm_bt<0><<<dim3(16, 32), 256, 0, stream>>>(Xb, WT, Qb, Kb, Vb, nullptr,
                                                     cosp, sinp, 2048);
        transpose_cast<<<dim3(64, 64), 256, 0, stream>>>(Wv, WT);
        gemm_bt<0><<<dim3(16, 32), 256, 0, stream>>>(Xb, WT, Qb, Kb, Vb, nullptr,
                                                     cosp, sinp, 4096);
        attn_kernel<<<dim3(16, 32), 256, 0, stream>>>(Qb, Kb, Vb, Xb /*Aout*/);
        transpose_cast<<<dim3(64, 64), 256, 0, stream>>>(Wo, WT);
        gemm_bt<2><<<dim3(16, 32), 256, 0, stream>>>(Xb, WT, nullptr, nullptr, nullptr,
                                                     (float*)d_out, cosp, sinp, 0);
    }
}

// Round 3
// 395.630 us; speedup vs baseline: 1.1414x; 1.1414x over previous
//
#include <hip/hip_runtime.h>

typedef short bf16x8 __attribute__((ext_vector_type(8)));
typedef float f32x4 __attribute__((ext_vector_type(4)));

#define HID   2048
#define S_LEN 2048
#define NH    16
#define HD    128
#define BATCH 2
#define NROWS (BATCH * S_LEN)  // 4096

__device__ __forceinline__ float bf2f(unsigned short u) {
    union { unsigned int i; float f; } v;
    v.i = ((unsigned int)u) << 16;
    return v.f;
}
__device__ __forceinline__ unsigned short f2bf(float f) {
    union { float f; unsigned int i; } v;
    v.f = f;
    unsigned int u = v.i;
    return (unsigned short)((u + 0x7fffu + ((u >> 16) & 1u)) >> 16);
}

// packed f32x2 -> bf16x2 (RNE). Prefer HW v_cvt_pk_bf16_f32 on gfx950.
__device__ __forceinline__ unsigned int pkbf(float a, float b) {
#if defined(__has_builtin) && __has_builtin(__builtin_amdgcn_cvt_pk_bf16_f32)
    typedef __bf16 bf2_t __attribute__((ext_vector_type(2)));
    bf2_t v = __builtin_amdgcn_cvt_pk_bf16_f32(a, b);
    unsigned int u;
    __builtin_memcpy(&u, &v, 4);
    return u;
#else
    return (unsigned int)f2bf(a) | ((unsigned int)f2bf(b) << 16);
#endif
}

__device__ __forceinline__ float exp2_fast(float x) {
#if defined(__has_builtin) && __has_builtin(__builtin_amdgcn_exp2f)
    return __builtin_amdgcn_exp2f(x);
#else
    return __expf(x * 0.6931471805599453f);
#endif
}

// async global->LDS, 16B per lane. LDS dest = wave-uniform base + lane*16B.
__device__ __forceinline__ void async16(const unsigned short* g, unsigned short* l) {
    __builtin_amdgcn_global_load_lds(
        (const __attribute__((address_space(1))) unsigned int*)g,
        (__attribute__((address_space(3))) unsigned int*)l, 16, 0, 0);
}

// ---------------- prep: z<3 -> transpose+cast W_z; z==3 -> cast hs -> bf16 ----------------
__global__ __launch_bounds__(256) void prep(const float* __restrict__ hs,
                                            const float* __restrict__ Wa,
                                            const float* __restrict__ Wb,
                                            const float* __restrict__ Wc,
                                            unsigned short* __restrict__ Xb,
                                            unsigned short* __restrict__ WT) {
    int z = blockIdx.z;
    int t = threadIdx.x;
    if (z == 3) {
        size_t idx = (((size_t)blockIdx.y * 64 + blockIdx.x) * 256 + t) * 8;
        float4 v0 = *(const float4*)(hs + idx);
        float4 v1 = *(const float4*)(hs + idx + 4);
        uint4 o;
        o.x = pkbf(v0.x, v0.y);
        o.y = pkbf(v0.z, v0.w);
        o.z = pkbf(v1.x, v1.y);
        o.w = pkbf(v1.z, v1.w);
        *(uint4*)(Xb + idx) = o;
        return;
    }
    __shared__ float tile[32][33];
    int tx = t & 31, ty = t >> 5;  // 32 x 8
    int bx = blockIdx.x, by = blockIdx.y;
    const float* W = (z == 0) ? Wa : ((z == 1) ? Wb : Wc);
    unsigned short* dst = WT + (size_t)z * HID * HID;
#pragma unroll
    for (int i = 0; i < 4; i++)
        tile[ty + i * 8][tx] = W[(size_t)(by * 32 + ty + i * 8) * HID + bx * 32 + tx];
    __syncthreads();
#pragma unroll
    for (int i = 0; i < 4; i++)
        dst[(size_t)(bx * 32 + ty + i * 8) * HID + by * 32 + tx] = f2bf(tile[tx][ty + i * 8]);
}

// ---------------- standalone transpose + cast (used for Wo) ----------------
__global__ __launch_bounds__(256) void transpose_cast(const float* __restrict__ W,
                                                      unsigned short* __restrict__ WT) {
    __shared__ float tile[32][33];
    int t = threadIdx.x;
    int tx = t & 31, ty = t >> 5;
    int bx = blockIdx.x, by = blockIdx.y;
#pragma unroll
    for (int i = 0; i < 4; i++)
        tile[ty + i * 8][tx] = W[(size_t)(by * 32 + ty + i * 8) * HID + bx * 32 + tx];
    __syncthreads();
#pragma unroll
    for (int i = 0; i < 4; i++)
        WT[(size_t)(bx * 32 + ty + i * 8) * HID + by * 32 + tx] = f2bf(tile[tx][ty + i * 8]);
}

// ===========================================================================
// 128x384-tile QKV GEMM. T3+T4+T5 pipeline: BK=32, ring-3 LDS (96 KB),
// prefetch depth 2, counted vmcnt(4), setprio around MFMA clusters.
// Grid = 32x16 = 512 blocks = exactly 2 full CU-rounds (no tail idle).
//
// LDS slot (32 KB): A[128][32] (4096 sh) + B[384][32] (12288 sh), 64B rows.
// Conflict-free BK=32 swizzle (64B rows):
//   store: LDS row r, 16B-pos p holds global chunk p ^ ((r>>1)&3)
//          (DMA dest linear: lane l -> row base+(l>>2), pos l&3, so the
//           global SOURCE chunk is (l&3) ^ ((l>>3)&3) — rule 21)
//   read:  fragment (row base+c, k-chunk quad) at pos quad ^ ((c>>1)&3)
//   bank group = (c&1)*4 + (quad ^ ((c>>1)&3)) — bijective per lane-octet.
//
// Per K-tile (64 of them): P0 {issue A(kt+2); ds_read af0,1 + bfr0..5; bar;
// prio1; 12 MFMA; prio0; bar}  P1 {issue B(kt+2)x3; ds_read af2,3; vmcnt(4);
// bar; prio1; 12 MFMA; prio0; bar}. vmcnt never drained to 0 in-loop.
// Tail clamps ktn to 63 (re-issues identical bytes; preserves the count).
//
// Epilogue: per 16-col subtile mat = colbase>>11 (always uniform; 384-tiles
// cross Q|K|V boundaries). RoPE partner col^64 is in-block/in-head; swap via
// LDS per mt-iteration with computed partner (wn',nt').
// ===========================================================================
__global__ __launch_bounds__(512, 2) void gemm_qkv(const unsigned short* __restrict__ A,
                                                   const unsigned short* __restrict__ Bt,
                                                   unsigned short* __restrict__ Qo,
                                                   unsigned short* __restrict__ Ko,
                                                   unsigned short* __restrict__ Vo,
                                                   const float* __restrict__ cosp,
                                                   const float* __restrict__ sinp) {
    __shared__ unsigned short SM[49152];  // 96 KB: 3 ring slots of 16384 shorts
    int t = threadIdx.x;
    int w = t >> 6, lane = t & 63;
    int wm = w >> 2, wn = w & 3;          // 2 x 4 waves over 128 x 384
    int c = lane & 15, quad = lane >> 4;

    // XCD-chunked bijective swizzle (512 % 8 == 0). bx-major per XCD:
    // each XCD covers 2 N-panels (3 MB, L2-fit) x all 32 M-tiles.
    int bid = blockIdx.x;
    int wgid = (bid & 7) * 64 + (bid >> 3);
    int bx = wgid >> 5, by = wgid & 31;
    int m0 = by * 128, n0 = bx * 384;

    // staging: lane l -> row (l>>2), LDS pos (l&3); source chunk pre-swizzled.
    int srow = lane >> 2;
    int schk = (lane & 3) ^ ((lane >> 3) & 3);
    const unsigned short* Agp = A  + (size_t)(m0 + w * 16 + srow) * HID + schk * 8;
    const unsigned short* Bgp = Bt + (size_t)(n0 + w * 16 + srow) * HID + schk * 8;

    f32x4 zero = {0.f, 0.f, 0.f, 0.f};
    f32x4 acc[4][6];
#pragma unroll
    for (int i = 0; i < 4; i++)
#pragma unroll
        for (int j = 0; j < 6; j++) acc[i][j] = zero;

    // prologue: stage kt0 -> slot0, kt1 -> slot1 (4 issues each)
#pragma unroll
    for (int p = 0; p < 2; p++) {
        unsigned short* S = SM + p * 16384;
        async16(Agp + p * 32, S + w * 512);
#pragma unroll
        for (int j = 0; j < 3; j++)
            async16(Bgp + p * 32 + (size_t)j * 128 * HID, S + 4096 + j * 4096 + w * 512);
    }
    __builtin_amdgcn_s_waitcnt(0x0F74);  // vmcnt(4): kt0 landed, kt1 in flight
    __builtin_amdgcn_s_barrier();

    int rofs = (quad ^ ((c >> 1) & 3)) * 8;  // swizzled 16B-pos for frag reads

    int scur = 0;
    for (int kt = 0; kt < 64; kt++) {
        const unsigned short* Sa = SM + scur * 16384;
        const unsigned short* Sb = Sa + 4096;
        int ktn = kt + 2; if (ktn > 63) ktn = 63;
        int snx = scur + 2; if (snx >= 3) snx -= 3;
        unsigned short* Sn = SM + snx * 16384;

        // ---- phase 0 ----
        async16(Agp + ktn * 32, Sn + w * 512);
        bf16x8 af[2], bfr[6];
#pragma unroll
        for (int mt = 0; mt < 2; mt++)
            af[mt] = *(const bf16x8*)(Sa + (wm * 64 + mt * 16 + c) * 32 + rofs);
#pragma unroll
        for (int nt = 0; nt < 6; nt++)
            bfr[nt] = *(const bf16x8*)(Sb + (wn * 96 + nt * 16 + c) * 32 + rofs);
        __builtin_amdgcn_s_barrier();
        __builtin_amdgcn_s_setprio(1);
#pragma unroll
        for (int mt = 0; mt < 2; mt++)
#pragma unroll
            for (int nt = 0; nt < 6; nt++)
                acc[mt][nt] = __builtin_amdgcn_mfma_f32_16x16x32_bf16(af[mt], bfr[nt],
                                                                      acc[mt][nt], 0, 0, 0);
        __builtin_amdgcn_s_setprio(0);
        __builtin_amdgcn_s_barrier();

        // ---- phase 1 ----
#pragma unroll
        for (int j = 0; j < 3; j++)
            async16(Bgp + ktn * 32 + (size_t)j * 128 * HID, Sn + 4096 + j * 4096 + w * 512);
        bf16x8 ag[2];
#pragma unroll
        for (int mt = 0; mt < 2; mt++)
            ag[mt] = *(const bf16x8*)(Sa + (wm * 64 + (mt + 2) * 16 + c) * 32 + rofs);
        __builtin_amdgcn_s_waitcnt(0x0F74);  // vmcnt(4): kt+1 resident after barrier
        __builtin_amdgcn_s_barrier();
        __builtin_amdgcn_s_setprio(1);
#pragma unroll
        for (int mt = 0; mt < 2; mt++)
#pragma unroll
            for (int nt = 0; nt < 6; nt++)
                acc[mt + 2][nt] = __builtin_amdgcn_mfma_f32_16x16x32_bf16(ag[mt], bfr[nt],
                                                                          acc[mt + 2][nt], 0, 0, 0);
        __builtin_amdgcn_s_setprio(0);
        __builtin_amdgcn_s_barrier();

        scur = (scur + 1 == 3) ? 0 : scur + 1;
    }

    __syncthreads();  // full drain (incl. dup tail DMA) before SM reuse

    // ---- epilogue: per-subtile dispatch; RoPE partner = col^64 via LDS swap ----
    // Swap slab per mt: (wave,nt) slot of 64 lanes x ushort4 = 256 shorts.
#pragma unroll
    for (int mt = 0; mt < 4; mt++) {
#pragma unroll
        for (int nt = 0; nt < 6; nt++) {
            ushort4 o;
            o.x = f2bf(acc[mt][nt][0]);
            o.y = f2bf(acc[mt][nt][1]);
            o.z = f2bf(acc[mt][nt][2]);
            o.w = f2bf(acc[mt][nt][3]);
            *(ushort4*)(SM + (w * 6 + nt) * 256 + lane * 4) = o;
        }
        __syncthreads();
#pragma unroll
        for (int nt = 0; nt < 6; nt++) {
            int colbase = n0 + wn * 96 + nt * 16;
            int mat = colbase >> 11;            // uniform within 16-col subtile
            int h = (colbase & 2047) >> 7;
            int dc = (colbase & 127) + c;
            if (mat == 2) {
                // V^T: [b][h][d][s], 4 consecutive s per lane -> packed 8B store
                int row0 = m0 + wm * 64 + mt * 16 + quad * 4;
                int b = row0 >> 11, s = row0 & 2047;
                ushort4 o;
                o.x = f2bf(acc[mt][nt][0]);
                o.y = f2bf(acc[mt][nt][1]);
                o.z = f2bf(acc[mt][nt][2]);
                o.w = f2bf(acc[mt][nt][3]);
                *(ushort4*)(Vo + ((size_t)(b * NH + h) * HD + dc) * S_LEN + s) = o;
            } else {
                int q2 = (wn * 96 + nt * 16) ^ 64;   // partner subtile offset in tile
                int wn2 = q2 / 96;
                int nt2 = (q2 - wn2 * 96) >> 4;
                ushort4 pv = *(const ushort4*)(SM + ((wm * 4 + wn2) * 6 + nt2) * 256 + lane * 4);
                float part[4] = {bf2f(pv.x), bf2f(pv.y), bf2f(pv.z), bf2f(pv.w)};
                float sgn = ((colbase >> 6) & 1) ? 1.0f : -1.0f;
                unsigned short* Cb = (mat == 0) ? Qo : Ko;
                float scl = (mat == 0) ? 0.12751743f : 1.0f;  // log2(e)/sqrt(128) in Q
#pragma unroll
                for (int r = 0; r < 4; r++) {
                    int row = m0 + wm * 64 + mt * 16 + quad * 4 + r;
                    int b = row >> 11, s = row & 2047;
                    float cv = cosp[s * HD + dc], sv = sinp[s * HD + dc];
                    float out = (acc[mt][nt][r] * cv + sgn * part[r] * sv) * scl;
                    Cb[((size_t)(b * NH + h) * S_LEN + s) * HD + dc] = f2bf(out);
                }
            }
        }
        __syncthreads();
    }
}

// ---------------- bf16 GEMM, BK=64 XOR-swizzled staging (legacy 128^2) ----------------
// Kept for the fallback path and for the output GEMM (MODE 2: 512 blocks).
template <int MODE>
__global__ __launch_bounds__(256, 2) void gemm_bt(const unsigned short* __restrict__ A,
                                                  const unsigned short* __restrict__ Bt,
                                                  unsigned short* __restrict__ Qo,
                                                  unsigned short* __restrict__ Ko,
                                                  unsigned short* __restrict__ Vo,
                                                  float* __restrict__ Fo,
                                                  const float* __restrict__ cosp,
                                                  const float* __restrict__ sinp,
                                                  int n_shift) {
    __shared__ unsigned short SM[16384];       // 32 KB: Asm(16K) + Bsm(16K); reused for rope swap
    unsigned short* Asm = SM;                  // 128 rows x 64 shorts, XOR-swizzled cols
    unsigned short* Bsm = SM + 8192;
    int t = threadIdx.x;
    int wave = t >> 6, lane = t & 63;
    int wm = wave >> 1, wn = wave & 1;
    int c = lane & 15, quad = lane >> 4;
    int m0 = blockIdx.y * 128, nloc = blockIdx.x * 128;

    int lr = lane >> 3;
    int cb = (lane & 7) ^ (lr & 7);
    const unsigned short* Ag = A + (size_t)(m0 + wave * 32 + lr) * HID + cb * 8;
    const unsigned short* Bg = Bt + (size_t)(nloc + wave * 32 + lr) * HID + cb * 8;
    unsigned short* Al = Asm + wave * 2048;  // 32 rows * 64 shorts
    unsigned short* Bl = Bsm + wave * 2048;

    f32x4 zero = {0.f, 0.f, 0.f, 0.f};
    f32x4 acc[4][4];
#pragma unroll
    for (int i = 0; i < 4; i++)
#pragma unroll
        for (int j = 0; j < 4; j++) acc[i][j] = zero;

    for (int it = 0; it < 32; it++) {
        int k0 = it * 64;
#pragma unroll
        for (int j = 0; j < 4; j++) {
            async16(Ag + k0 + j * 8 * HID, Al + j * 512);
            async16(Bg + k0 + j * 8 * HID, Bl + j * 512);
        }
        __syncthreads();
#pragma unroll
        for (int kk = 0; kk < 2; kk++) {
            bf16x8 af[4], bfr[4];
#pragma unroll
            for (int mt = 0; mt < 4; mt++)
                af[mt] = *(const bf16x8*)(Asm + (wm * 64 + mt * 16 + c) * 64 +
                                          (((kk * 4 + quad) ^ (c & 7)) * 8));
#pragma unroll
            for (int nt = 0; nt < 4; nt++)
                bfr[nt] = *(const bf16x8*)(Bsm + (wn * 64 + nt * 16 + c) * 64 +
                                           (((kk * 4 + quad) ^ (c & 7)) * 8));
#pragma unroll
            for (int mt = 0; mt < 4; mt++)
#pragma unroll
                for (int nt = 0; nt < 4; nt++)
                    acc[mt][nt] = __builtin_amdgcn_mfma_f32_16x16x32_bf16(af[mt], bfr[nt],
                                                                          acc[mt][nt], 0, 0, 0);
        }
        __syncthreads();
    }

    if (MODE == 2) {
#pragma unroll
        for (int mt = 0; mt < 4; mt++)
#pragma unroll
            for (int nt = 0; nt < 4; nt++)
#pragma unroll
                for (int r = 0; r < 4; r++) {
                    int row = m0 + wm * 64 + mt * 16 + quad * 4 + r;
                    int col = nloc + wn * 64 + nt * 16 + c;
                    Fo[(size_t)row * HID + col] = acc[mt][nt][r];
                }
    } else {
        int nglob0 = n_shift + nloc;
        int mat = nglob0 >> 11;         // block-uniform
        int h = (nglob0 & 2047) >> 7;   // block covers exactly one head (128 cols)
        if (mat == 2) {
#pragma unroll
            for (int mt = 0; mt < 4; mt++)
#pragma unroll
                for (int nt = 0; nt < 4; nt++) {
                    int d = wn * 64 + nt * 16 + c;
                    int row0 = m0 + wm * 64 + mt * 16 + quad * 4;
                    int b = row0 >> 11, s = row0 & 2047;
                    ushort4 o;
                    o.x = f2bf(acc[mt][nt][0]);
                    o.y = f2bf(acc[mt][nt][1]);
                    o.z = f2bf(acc[mt][nt][2]);
                    o.w = f2bf(acc[mt][nt][3]);
                    *(ushort4*)(Vo + ((size_t)(b * NH + h) * HD + d) * S_LEN + s) = o;
                }
        } else {
            unsigned short* Cb = (mat == 0) ? Qo : Ko;
            float scl = (mat == 0) ? 0.12751743f : 1.0f;
            __syncthreads();
#pragma unroll
            for (int mt = 0; mt < 4; mt++)
#pragma unroll
                for (int nt = 0; nt < 4; nt++) {
                    ushort4 o;
                    o.x = f2bf(acc[mt][nt][0]);
                    o.y = f2bf(acc[mt][nt][1]);
                    o.z = f2bf(acc[mt][nt][2]);
                    o.w = f2bf(acc[mt][nt][3]);
                    *(ushort4*)(SM + (mt * 4 + nt) * 1024 + t * 4) = o;
                }
            __syncthreads();
            int partner = (wm * 2 + (wn ^ 1)) * 64 + lane;
            float sgn = wn ? 1.0f : -1.0f;
#pragma unroll
            for (int mt = 0; mt < 4; mt++) {
#pragma unroll
                for (int nt = 0; nt < 4; nt++) {
                    ushort4 pv = *(const ushort4*)(SM + (mt * 4 + nt) * 1024 + partner * 4);
                    float part[4] = {bf2f(pv.x), bf2f(pv.y), bf2f(pv.z), bf2f(pv.w)};
                    int col = wn * 64 + nt * 16 + c;
#pragma unroll
                    for (int r = 0; r < 4; r++) {
                        int row = m0 + wm * 64 + mt * 16 + quad * 4 + r;
                        int b = row >> 11, s = row & 2047;
                        float cv = cosp[s * HD + col], sv = sinp[s * HD + col];
                        float out = (acc[mt][nt][r] * cv + sgn * part[r] * sv) * scl;
                        Cb[((size_t)(b * NH + h) * S_LEN + s) * HD + col] = f2bf(out);
                    }
                }
            }
        }
    }
}

// ---------------- flash attention (no-max online softmax, S^T formulation) ----------------
#define PKS 72  // P row stride in shorts (144B = 9*16: b128-aligned, conflict-free)
__global__ __launch_bounds__(256, 2) void attn_kernel(const unsigned short* __restrict__ Q,
                                                      const unsigned short* __restrict__ Kg,
                                                      const unsigned short* __restrict__ Vt,
                                                      unsigned short* __restrict__ Aout) {
    __shared__ unsigned short Ksm[64 * 128];            // 16 KB, [key][d], XOR-swizzled chunks
    __shared__ unsigned short Vsm[128 * 64];            // 16 KB, [d][key], XOR-swizzled chunks
    __shared__ __align__(16) unsigned short Psm[4 * 2 * 16 * PKS];  // 18 KB
    int bh = blockIdx.y;
    int b = bh >> 4, h = bh & 15;
    int t = threadIdx.x;
    int wave = t >> 6, lane = t & 63;
    int c = lane & 15, quad = lane >> 4;
    int q0 = blockIdx.x * 128 + wave * 32;
    const unsigned short* Qp = Q + (size_t)bh * S_LEN * HD;
    const unsigned short* Kp = Kg + (size_t)bh * S_LEN * HD;
    const unsigned short* Vp = Vt + (size_t)bh * HD * S_LEN;

    bf16x8 qf[2][4];
#pragma unroll
    for (int qn = 0; qn < 2; qn++)
#pragma unroll
        for (int kk = 0; kk < 4; kk++)
            qf[qn][kk] = *(const bf16x8*)(Qp + (size_t)(q0 + qn * 16 + c) * HD + kk * 32 + quad * 8);

    f32x4 zero = {0.f, 0.f, 0.f, 0.f};
    f32x4 o_acc[2][8];
#pragma unroll
    for (int qn = 0; qn < 2; qn++)
#pragma unroll
        for (int nt = 0; nt < 8; nt++) o_acc[qn][nt] = zero;
    float lsum[2] = {0.f, 0.f};

    for (int key0 = 0; key0 < S_LEN; key0 += 64) {
#pragma unroll
        for (int j = 0; j < 4; j++) {
            int fc = (wave * 4 + j) * 64 + lane;
            int rK = fc >> 4, cbK = (fc & 15) ^ (rK & 15);
            async16(Kp + (size_t)(key0 + rK) * HD + cbK * 8, Ksm + (wave * 4 + j) * 512);
            int rV = fc >> 3, cbV = (fc & 7) ^ (rV & 7);
            async16(Vp + (size_t)rV * S_LEN + key0 + cbV * 8, Vsm + (wave * 4 + j) * 512);
        }
        __syncthreads();

        f32x4 sacc[4][2];
#pragma unroll
        for (int km = 0; km < 4; km++)
#pragma unroll
            for (int qn = 0; qn < 2; qn++) sacc[km][qn] = zero;
#pragma unroll
        for (int kk = 0; kk < 4; kk++) {
            bf16x8 kfr[4];
#pragma unroll
            for (int km = 0; km < 4; km++)
                kfr[km] = *(const bf16x8*)(Ksm + (km * 16 + c) * HD + (((kk * 4 + quad) ^ c)) * 8);
#pragma unroll
            for (int km = 0; km < 4; km++)
#pragma unroll
                for (int qn = 0; qn < 2; qn++)
                    sacc[km][qn] = __builtin_amdgcn_mfma_f32_16x16x32_bf16(kfr[km], qf[qn][kk],
                                                                           sacc[km][qn], 0, 0, 0);
        }

#pragma unroll
        for (int qn = 0; qn < 2; qn++) {
#pragma unroll
            for (int km = 0; km < 4; km++) {
                float e0 = exp2_fast(sacc[km][qn][0]);
                float e1 = exp2_fast(sacc[km][qn][1]);
                float e2 = exp2_fast(sacc[km][qn][2]);
                float e3 = exp2_fast(sacc[km][qn][3]);
                lsum[qn] += (e0 + e1) + (e2 + e3);
                uint2 pk;
                pk.x = pkbf(e0, e1);
                pk.y = pkbf(e2, e3);
                *(uint2*)(Psm + ((wave * 2 + qn) * 16 + c) * PKS + km * 16 + quad * 4) = pk;
            }
        }
        asm volatile("" ::: "memory");
        __builtin_amdgcn_s_waitcnt(0xc07f);  // lgkmcnt(0), vmcnt/expcnt unaffected
        asm volatile("" ::: "memory");

#pragma unroll
        for (int kf = 0; kf < 2; kf++) {
            bf16x8 pf[2];
#pragma unroll
            for (int qn = 0; qn < 2; qn++)
                pf[qn] = *(const bf16x8*)(Psm + ((wave * 2 + qn) * 16 + c) * PKS + kf * 32 + quad * 8);
#pragma unroll
            for (int nt = 0; nt < 8; nt++) {
                bf16x8 vf = *(const bf16x8*)(Vsm + (nt * 16 + c) * 64 +
                                             (((kf * 4 + quad) ^ (c & 7))) * 8);
#pragma unroll
                for (int qn = 0; qn < 2; qn++)
                    o_acc[qn][nt] = __builtin_amdgcn_mfma_f32_16x16x32_bf16(pf[qn], vf,
                                                                            o_acc[qn][nt], 0, 0, 0);
            }
        }
        __syncthreads();
    }

#pragma unroll
    for (int qn = 0; qn < 2; qn++) {
        lsum[qn] += __shfl_xor(lsum[qn], 16);
        lsum[qn] += __shfl_xor(lsum[qn], 32);
    }
    float inv[2][4];
#pragma unroll
    for (int qn = 0; qn < 2; qn++)
#pragma unroll
        for (int r = 0; r < 4; r++)
            inv[qn][r] = 1.0f / __shfl(lsum[qn], quad * 4 + r);

#pragma unroll
    for (int qn = 0; qn < 2; qn++) {
#pragma unroll
        for (int r = 0; r < 4; r++) {
            int srow = q0 + qn * 16 + quad * 4 + r;
            size_t base = ((size_t)(b * S_LEN + srow)) * HID + h * HD;
#pragma unroll
            for (int nt = 0; nt < 8; nt++)
                Aout[base + nt * 16 + c] = f2bf(o_acc[qn][nt][r] * inv[qn][r]);
        }
    }
}

extern "C" void kernel_launch(void* const* d_in, const int* in_sizes, int n_in,
                              void* d_out, int out_size, void* d_ws, size_t ws_size,
                              hipStream_t stream) {
    const float* hs   = (const float*)d_in[0];
    const float* cosp = (const float*)d_in[1];
    const float* sinp = (const float*)d_in[2];
    const float* Wq   = (const float*)d_in[3];
    const float* Wk   = (const float*)d_in[4];
    const float* Wv   = (const float*)d_in[5];
    const float* Wo   = (const float*)d_in[6];

    char* ws = (char*)d_ws;
    unsigned short* Xb = (unsigned short*)(ws);                      // 0-16 MB (reused as Aout)
    unsigned short* Qb = (unsigned short*)(ws + (16ull << 20));      // 16-32
    unsigned short* Kb = (unsigned short*)(ws + (32ull << 20));      // 32-48
    unsigned short* Vb = (unsigned short*)(ws + (48ull << 20));      // 48-64
    unsigned short* WT = (unsigned short*)(ws + (64ull << 20));      // 64-88 fused / 64-72 single

    const bool fused = ws_size >= (88ull << 20);

    if (fused) {
        // 1. cast + 3 weight transposes in one launch
        prep<<<dim3(64, 64, 4), 256, 0, stream>>>(hs, Wq, Wk, Wv, Xb, WT);
        // 2. fused QKV GEMM (128x384 tile, perfect 512-block grid) + RoPE epilogue
        gemm_qkv<<<dim3(512), 512, 0, stream>>>(Xb, WT, Qb, Kb, Vb, cosp, sinp);
        // 3. flash attention
        attn_kernel<<<dim3(16, 32), 256, 0, stream>>>(Qb, Kb, Vb, Xb /*Aout*/);
        // 4. Wo transpose into dead Qb region
        unsigned short* WoT = (unsigned short*)(ws + (16ull << 20));
        transpose_cast<<<dim3(64, 64), 256, 0, stream>>>(Wo, WoT);
        // 5. output GEMM, fp32 direct to d_out
        gemm_bt<2><<<dim3(16, 32), 256, 0, stream>>>(Xb, WoT, nullptr, nullptr, nullptr,
                                                     (float*)d_out, cosp, sinp, 0);
    } else {
        prep<<<dim3(64, 64, 1), 256, 0, stream>>>(hs, Wq, Wq, Wq, Xb, WT);
        prep<<<dim3(64, 64, 4), 256, 0, stream>>>(hs, Wq, Wq, Wq, Xb, WT);  // cast + Wq^T
        gemm_bt<0><<<dim3(16, 32), 256, 0, stream>>>(Xb, WT, Qb, Kb, Vb, nullptr,
                                                     cosp, sinp, 0);
        transpose_cast<<<dim3(64, 64), 256, 0, stream>>>(Wk, WT);
        gemm_bt<0><<<dim3(16, 32), 256, 0, stream>>>(Xb, WT, Qb, Kb, Vb, nullptr,
                                                     cosp, sinp, 2048);
        transpose_cast<<<dim3(64, 64), 256, 0, stream>>>(Wv, WT);
        gemm_bt<0><<<dim3(16, 32), 256, 0, stream>>>(Xb, WT, Qb, Kb, Vb, nullptr,
                                                     cosp, sinp, 4096);
        attn_kernel<<<dim3(16, 32), 256, 0, stream>>>(Qb, Kb, Vb, Xb /*Aout*/);
        transpose_cast<<<dim3(64, 64), 256, 0, stream>>>(Wo, WT);
        gemm_bt<2><<<dim3(16, 32), 256, 0, stream>>>(Xb, WT, nullptr, nullptr, nullptr,
                                                     (float*)d_out, cosp, sinp, 0);
    }
}

// Round 4
// 387.519 us; speedup vs baseline: 1.1653x; 1.0209x over previous
//
#include <hip/hip_runtime.h>

typedef short bf16x8 __attribute__((ext_vector_type(8)));
typedef float f32x4 __attribute__((ext_vector_type(4)));

#define HID   2048
#define S_LEN 2048
#define NH    16
#define HD    128
#define BATCH 2
#define NROWS (BATCH * S_LEN)  // 4096

__device__ __forceinline__ float bf2f(unsigned short u) {
    union { unsigned int i; float f; } v;
    v.i = ((unsigned int)u) << 16;
    return v.f;
}
__device__ __forceinline__ unsigned short f2bf(float f) {
    union { float f; unsigned int i; } v;
    v.f = f;
    unsigned int u = v.i;
    return (unsigned short)((u + 0x7fffu + ((u >> 16) & 1u)) >> 16);
}

// packed f32x2 -> bf16x2 (RNE). Prefer HW v_cvt_pk_bf16_f32 on gfx950.
__device__ __forceinline__ unsigned int pkbf(float a, float b) {
#if defined(__has_builtin) && __has_builtin(__builtin_amdgcn_cvt_pk_bf16_f32)
    typedef __bf16 bf2_t __attribute__((ext_vector_type(2)));
    bf2_t v = __builtin_amdgcn_cvt_pk_bf16_f32(a, b);
    unsigned int u;
    __builtin_memcpy(&u, &v, 4);
    return u;
#else
    return (unsigned int)f2bf(a) | ((unsigned int)f2bf(b) << 16);
#endif
}

__device__ __forceinline__ float exp2_fast(float x) {
#if defined(__has_builtin) && __has_builtin(__builtin_amdgcn_exp2f)
    return __builtin_amdgcn_exp2f(x);
#else
    return __expf(x * 0.6931471805599453f);
#endif
}

// async global->LDS, 16B per lane. LDS dest = wave-uniform base + lane*16B.
__device__ __forceinline__ void async16(const unsigned short* g, unsigned short* l) {
    __builtin_amdgcn_global_load_lds(
        (const __attribute__((address_space(1))) unsigned int*)g,
        (__attribute__((address_space(3))) unsigned int*)l, 16, 0, 0);
}

// ---------------- prep: z<3 -> transpose+cast W_z; z==3 -> cast hs -> bf16 ----------------
__global__ __launch_bounds__(256) void prep(const float* __restrict__ hs,
                                            const float* __restrict__ Wa,
                                            const float* __restrict__ Wb,
                                            const float* __restrict__ Wc,
                                            unsigned short* __restrict__ Xb,
                                            unsigned short* __restrict__ WT) {
    int z = blockIdx.z;
    int t = threadIdx.x;
    if (z == 3) {
        size_t idx = (((size_t)blockIdx.y * 64 + blockIdx.x) * 256 + t) * 8;
        float4 v0 = *(const float4*)(hs + idx);
        float4 v1 = *(const float4*)(hs + idx + 4);
        uint4 o;
        o.x = pkbf(v0.x, v0.y);
        o.y = pkbf(v0.z, v0.w);
        o.z = pkbf(v1.x, v1.y);
        o.w = pkbf(v1.z, v1.w);
        *(uint4*)(Xb + idx) = o;
        return;
    }
    __shared__ float tile[32][33];
    int tx = t & 31, ty = t >> 5;  // 32 x 8
    int bx = blockIdx.x, by = blockIdx.y;
    const float* W = (z == 0) ? Wa : ((z == 1) ? Wb : Wc);
    unsigned short* dst = WT + (size_t)z * HID * HID;
#pragma unroll
    for (int i = 0; i < 4; i++)
        tile[ty + i * 8][tx] = W[(size_t)(by * 32 + ty + i * 8) * HID + bx * 32 + tx];
    __syncthreads();
#pragma unroll
    for (int i = 0; i < 4; i++)
        dst[(size_t)(bx * 32 + ty + i * 8) * HID + by * 32 + tx] = f2bf(tile[tx][ty + i * 8]);
}

// ---------------- standalone transpose + cast (used for Wo) ----------------
__global__ __launch_bounds__(256) void transpose_cast(const float* __restrict__ W,
                                                      unsigned short* __restrict__ WT) {
    __shared__ float tile[32][33];
    int t = threadIdx.x;
    int tx = t & 31, ty = t >> 5;
    int bx = blockIdx.x, by = blockIdx.y;
#pragma unroll
    for (int i = 0; i < 4; i++)
        tile[ty + i * 8][tx] = W[(size_t)(by * 32 + ty + i * 8) * HID + bx * 32 + tx];
    __syncthreads();
#pragma unroll
    for (int i = 0; i < 4; i++)
        WT[(size_t)(bx * 32 + ty + i * 8) * HID + by * 32 + tx] = f2bf(tile[tx][ty + i * 8]);
}

// ===========================================================================
// 128x384-tile QKV GEMM. Ring-3 LDS (96 KB), BK=32, counted vmcnt(4),
// ONE barrier per K-tile, and REGISTER-DOUBLE-BUFFERED fragments:
// iteration kt issues ds_read of frags(kt+1) (bank B) right after the
// barrier, then runs the 24 MFMA of tile kt from bank A with NO dependency
// on those reads -> LDS pipe (~960 cyc/CU/K-tile) overlaps matrix pipe
// (~930 cyc) instead of serializing (the round-3 defect: same-phase
// consume forced lgkm drain before MFMA; max() vs sum()).
//
// Per K-tile kt:
//   STAGE(kt+2)            // 4 async16 -> slot (kt+2)%3 (clamped dup at tail)
//   vmcnt(4)               // drains tile kt+1's 4 loads (kt+2's stay in flight)
//   s_barrier              // publishes slot kt+1 to all waves; also orders
//                          //   slot-(kt-1) readers before the kt+2 overwrite
//   ds_read frags(kt+1) -> other bank   (10 x b128, conflict-free swizzle)
//   sched_barrier(0)       // pin reads above MFMAs (keep them async)
//   setprio(1); 24 MFMA on current bank; setprio(0)
// Implicit lgkmcnt for the new bank lands at the NEXT iteration's cluster.
// Loop hand-unrolled x2 for static bank swap (rule #20). 64 barriers total
// (was 256). Tail: stage clamps to tile 63 (identical-byte dup, preserves
// vmcnt count); final dummy ds_read of "frags(64)" from slot 1 is unused.
//
// Swizzle (64B rows, 16B chunks), conflict-free per lane-octet:
//   store: row r pos p holds global chunk p ^ ((r>>1)&3)  (linear DMA dest,
//          pre-swizzled global source — rule 21)
//   read:  (row c, k-chunk quad) at pos quad ^ ((c>>1)&3)
// ===========================================================================
__global__ __launch_bounds__(512, 2) void gemm_qkv(const unsigned short* __restrict__ A,
                                                   const unsigned short* __restrict__ Bt,
                                                   unsigned short* __restrict__ Qo,
                                                   unsigned short* __restrict__ Ko,
                                                   unsigned short* __restrict__ Vo,
                                                   const float* __restrict__ cosp,
                                                   const float* __restrict__ sinp) {
    __shared__ unsigned short SM[49152];  // 96 KB: 3 ring slots of 16384 shorts
    int t = threadIdx.x;
    int w = t >> 6, lane = t & 63;
    int wm = w >> 2, wn = w & 3;          // 2 x 4 waves over 128 x 384
    int c = lane & 15, quad = lane >> 4;

    // XCD-chunked bijective swizzle (512 % 8 == 0). bx-major per XCD.
    int bid = blockIdx.x;
    int wgid = (bid & 7) * 64 + (bid >> 3);
    int bx = wgid >> 5, by = wgid & 31;
    int m0 = by * 128, n0 = bx * 384;

    // staging: lane l -> row (l>>2), LDS pos (l&3); source chunk pre-swizzled.
    int srow = lane >> 2;
    int schk = (lane & 3) ^ ((lane >> 3) & 3);
    const unsigned short* Agp = A  + (size_t)(m0 + w * 16 + srow) * HID + schk * 8;
    const unsigned short* Bgp = Bt + (size_t)(n0 + w * 16 + srow) * HID + schk * 8;

    f32x4 zero = {0.f, 0.f, 0.f, 0.f};
    f32x4 acc[4][6];
#pragma unroll
    for (int i = 0; i < 4; i++)
#pragma unroll
        for (int j = 0; j < 6; j++) acc[i][j] = zero;

#define STAGE_QKV(KTN) {                                                        \
        unsigned short* Sn_ = SM + ((KTN) % 3) * 16384;                         \
        async16(Agp + (KTN) * 32, Sn_ + w * 512);                               \
        async16(Bgp + (KTN) * 32,                       Sn_ + 4096  + w * 512); \
        async16(Bgp + (KTN) * 32 + (size_t)128 * HID,   Sn_ + 8192  + w * 512); \
        async16(Bgp + (KTN) * 32 + (size_t)256 * HID,   Sn_ + 12288 + w * 512); }

#define DSREAD_QKV(SLOT, AF, BF) {                                              \
        const unsigned short* Sa_ = SM + (SLOT) * 16384;                        \
        const unsigned short* Sb_ = Sa_ + 4096;                                 \
        AF[0] = *(const bf16x8*)(Sa_ + (wm * 64 + 0 * 16 + c) * 32 + rofs);     \
        AF[1] = *(const bf16x8*)(Sa_ + (wm * 64 + 1 * 16 + c) * 32 + rofs);     \
        AF[2] = *(const bf16x8*)(Sa_ + (wm * 64 + 2 * 16 + c) * 32 + rofs);     \
        AF[3] = *(const bf16x8*)(Sa_ + (wm * 64 + 3 * 16 + c) * 32 + rofs);     \
        BF[0] = *(const bf16x8*)(Sb_ + (wn * 96 + 0 * 16 + c) * 32 + rofs);     \
        BF[1] = *(const bf16x8*)(Sb_ + (wn * 96 + 1 * 16 + c) * 32 + rofs);     \
        BF[2] = *(const bf16x8*)(Sb_ + (wn * 96 + 2 * 16 + c) * 32 + rofs);     \
        BF[3] = *(const bf16x8*)(Sb_ + (wn * 96 + 3 * 16 + c) * 32 + rofs);     \
        BF[4] = *(const bf16x8*)(Sb_ + (wn * 96 + 4 * 16 + c) * 32 + rofs);     \
        BF[5] = *(const bf16x8*)(Sb_ + (wn * 96 + 5 * 16 + c) * 32 + rofs); }

#define MFMA24(AF, BF) {                                                        \
        _Pragma("unroll")                                                       \
        for (int mt = 0; mt < 4; mt++)                                          \
            _Pragma("unroll")                                                   \
            for (int nt = 0; nt < 6; nt++)                                      \
                acc[mt][nt] = __builtin_amdgcn_mfma_f32_16x16x32_bf16(          \
                    AF[mt], BF[nt], acc[mt][nt], 0, 0, 0); }

    // prologue: stage tiles 0,1; land 0; read frags(0) into bank A.
    STAGE_QKV(0);
    STAGE_QKV(1);
    __builtin_amdgcn_s_waitcnt(0x0F74);  // vmcnt(4): tile 0 landed
    __builtin_amdgcn_s_barrier();

    int rofs = (quad ^ ((c >> 1) & 3)) * 8;  // swizzled 16B-pos for frag reads
    bf16x8 afA[4], bfA[6], afB[4], bfB[6];
    DSREAD_QKV(0, afA, bfA);

    for (int i = 0; i < 32; i++) {
        int kt0 = 2 * i, kt1 = 2 * i + 1;
        // ---- half 0: compute tile kt0 (bank A), prefetch frags(kt1) -> bank B
        int ktn0 = kt0 + 2; if (ktn0 > 63) ktn0 = 63;
        STAGE_QKV(ktn0);
        __builtin_amdgcn_s_waitcnt(0x0F74);  // tile kt0+1 resident after barrier
        __builtin_amdgcn_s_barrier();
        DSREAD_QKV(kt1 % 3, afB, bfB);
        __builtin_amdgcn_sched_barrier(0);
        __builtin_amdgcn_s_setprio(1);
        MFMA24(afA, bfA);
        __builtin_amdgcn_s_setprio(0);
        // ---- half 1: compute tile kt1 (bank B), prefetch frags(kt0+2) -> bank A
        int ktn1 = kt1 + 2; if (ktn1 > 63) ktn1 = 63;
        STAGE_QKV(ktn1);
        __builtin_amdgcn_s_waitcnt(0x0F74);  // tile kt1+1 resident after barrier
        __builtin_amdgcn_s_barrier();
        DSREAD_QKV((kt0 + 2) % 3, afA, bfA);  // i=31: dummy read (slot 1), unused
        __builtin_amdgcn_sched_barrier(0);
        __builtin_amdgcn_s_setprio(1);
        MFMA24(afB, bfB);
        __builtin_amdgcn_s_setprio(0);
    }

    __syncthreads();  // full drain (incl. dup tail DMA) before SM reuse

    // ---- epilogue: per-subtile dispatch; RoPE partner = col^64 via LDS swap ----
#pragma unroll
    for (int mt = 0; mt < 4; mt++) {
#pragma unroll
        for (int nt = 0; nt < 6; nt++) {
            ushort4 o;
            o.x = f2bf(acc[mt][nt][0]);
            o.y = f2bf(acc[mt][nt][1]);
            o.z = f2bf(acc[mt][nt][2]);
            o.w = f2bf(acc[mt][nt][3]);
            *(ushort4*)(SM + (w * 6 + nt) * 256 + lane * 4) = o;
        }
        __syncthreads();
#pragma unroll
        for (int nt = 0; nt < 6; nt++) {
            int colbase = n0 + wn * 96 + nt * 16;
            int mat = colbase >> 11;            // uniform within 16-col subtile
            int h = (colbase & 2047) >> 7;
            int dc = (colbase & 127) + c;
            if (mat == 2) {
                // V^T: [b][h][d][s], 4 consecutive s per lane -> packed 8B store
                int row0 = m0 + wm * 64 + mt * 16 + quad * 4;
                int b = row0 >> 11, s = row0 & 2047;
                ushort4 o;
                o.x = f2bf(acc[mt][nt][0]);
                o.y = f2bf(acc[mt][nt][1]);
                o.z = f2bf(acc[mt][nt][2]);
                o.w = f2bf(acc[mt][nt][3]);
                *(ushort4*)(Vo + ((size_t)(b * NH + h) * HD + dc) * S_LEN + s) = o;
            } else {
                int q2 = (wn * 96 + nt * 16) ^ 64;   // partner subtile offset in tile
                int wn2 = q2 / 96;
                int nt2 = (q2 - wn2 * 96) >> 4;
                ushort4 pv = *(const ushort4*)(SM + ((wm * 4 + wn2) * 6 + nt2) * 256 + lane * 4);
                float part[4] = {bf2f(pv.x), bf2f(pv.y), bf2f(pv.z), bf2f(pv.w)};
                float sgn = ((colbase >> 6) & 1) ? 1.0f : -1.0f;
                unsigned short* Cb = (mat == 0) ? Qo : Ko;
                float scl = (mat == 0) ? 0.12751743f : 1.0f;  // log2(e)/sqrt(128) in Q
#pragma unroll
                for (int r = 0; r < 4; r++) {
                    int row = m0 + wm * 64 + mt * 16 + quad * 4 + r;
                    int b = row >> 11, s = row & 2047;
                    float cv = cosp[s * HD + dc], sv = sinp[s * HD + dc];
                    float out = (acc[mt][nt][r] * cv + sgn * part[r] * sv) * scl;
                    Cb[((size_t)(b * NH + h) * S_LEN + s) * HD + dc] = f2bf(out);
                }
            }
        }
        __syncthreads();
    }
}

// ---------------- bf16 GEMM, BK=64 XOR-swizzled staging (legacy 128^2) ----------------
// Kept for the fallback path and for the output GEMM (MODE 2: 512 blocks).
template <int MODE>
__global__ __launch_bounds__(256, 2) void gemm_bt(const unsigned short* __restrict__ A,
                                                  const unsigned short* __restrict__ Bt,
                                                  unsigned short* __restrict__ Qo,
                                                  unsigned short* __restrict__ Ko,
                                                  unsigned short* __restrict__ Vo,
                                                  float* __restrict__ Fo,
                                                  const float* __restrict__ cosp,
                                                  const float* __restrict__ sinp,
                                                  int n_shift) {
    __shared__ unsigned short SM[16384];       // 32 KB: Asm(16K) + Bsm(16K); reused for rope swap
    unsigned short* Asm = SM;                  // 128 rows x 64 shorts, XOR-swizzled cols
    unsigned short* Bsm = SM + 8192;
    int t = threadIdx.x;
    int wave = t >> 6, lane = t & 63;
    int wm = wave >> 1, wn = wave & 1;
    int c = lane & 15, quad = lane >> 4;
    int m0 = blockIdx.y * 128, nloc = blockIdx.x * 128;

    int lr = lane >> 3;
    int cb = (lane & 7) ^ (lr & 7);
    const unsigned short* Ag = A + (size_t)(m0 + wave * 32 + lr) * HID + cb * 8;
    const unsigned short* Bg = Bt + (size_t)(nloc + wave * 32 + lr) * HID + cb * 8;
    unsigned short* Al = Asm + wave * 2048;  // 32 rows * 64 shorts
    unsigned short* Bl = Bsm + wave * 2048;

    f32x4 zero = {0.f, 0.f, 0.f, 0.f};
    f32x4 acc[4][4];
#pragma unroll
    for (int i = 0; i < 4; i++)
#pragma unroll
        for (int j = 0; j < 4; j++) acc[i][j] = zero;

    for (int it = 0; it < 32; it++) {
        int k0 = it * 64;
#pragma unroll
        for (int j = 0; j < 4; j++) {
            async16(Ag + k0 + j * 8 * HID, Al + j * 512);
            async16(Bg + k0 + j * 8 * HID, Bl + j * 512);
        }
        __syncthreads();
#pragma unroll
        for (int kk = 0; kk < 2; kk++) {
            bf16x8 af[4], bfr[4];
#pragma unroll
            for (int mt = 0; mt < 4; mt++)
                af[mt] = *(const bf16x8*)(Asm + (wm * 64 + mt * 16 + c) * 64 +
                                          (((kk * 4 + quad) ^ (c & 7)) * 8));
#pragma unroll
            for (int nt = 0; nt < 4; nt++)
                bfr[nt] = *(const bf16x8*)(Bsm + (wn * 64 + nt * 16 + c) * 64 +
                                           (((kk * 4 + quad) ^ (c & 7)) * 8));
#pragma unroll
            for (int mt = 0; mt < 4; mt++)
#pragma unroll
                for (int nt = 0; nt < 4; nt++)
                    acc[mt][nt] = __builtin_amdgcn_mfma_f32_16x16x32_bf16(af[mt], bfr[nt],
                                                                          acc[mt][nt], 0, 0, 0);
        }
        __syncthreads();
    }

    if (MODE == 2) {
#pragma unroll
        for (int mt = 0; mt < 4; mt++)
#pragma unroll
            for (int nt = 0; nt < 4; nt++)
#pragma unroll
                for (int r = 0; r < 4; r++) {
                    int row = m0 + wm * 64 + mt * 16 + quad * 4 + r;
                    int col = nloc + wn * 64 + nt * 16 + c;
                    Fo[(size_t)row * HID + col] = acc[mt][nt][r];
                }
    } else {
        int nglob0 = n_shift + nloc;
        int mat = nglob0 >> 11;         // block-uniform
        int h = (nglob0 & 2047) >> 7;   // block covers exactly one head (128 cols)
        if (mat == 2) {
#pragma unroll
            for (int mt = 0; mt < 4; mt++)
#pragma unroll
                for (int nt = 0; nt < 4; nt++) {
                    int d = wn * 64 + nt * 16 + c;
                    int row0 = m0 + wm * 64 + mt * 16 + quad * 4;
                    int b = row0 >> 11, s = row0 & 2047;
                    ushort4 o;
                    o.x = f2bf(acc[mt][nt][0]);
                    o.y = f2bf(acc[mt][nt][1]);
                    o.z = f2bf(acc[mt][nt][2]);
                    o.w = f2bf(acc[mt][nt][3]);
                    *(ushort4*)(Vo + ((size_t)(b * NH + h) * HD + d) * S_LEN + s) = o;
                }
        } else {
            unsigned short* Cb = (mat == 0) ? Qo : Ko;
            float scl = (mat == 0) ? 0.12751743f : 1.0f;
            __syncthreads();
#pragma unroll
            for (int mt = 0; mt < 4; mt++)
#pragma unroll
                for (int nt = 0; nt < 4; nt++) {
                    ushort4 o;
                    o.x = f2bf(acc[mt][nt][0]);
                    o.y = f2bf(acc[mt][nt][1]);
                    o.z = f2bf(acc[mt][nt][2]);
                    o.w = f2bf(acc[mt][nt][3]);
                    *(ushort4*)(SM + (mt * 4 + nt) * 1024 + t * 4) = o;
                }
            __syncthreads();
            int partner = (wm * 2 + (wn ^ 1)) * 64 + lane;
            float sgn = wn ? 1.0f : -1.0f;
#pragma unroll
            for (int mt = 0; mt < 4; mt++) {
#pragma unroll
                for (int nt = 0; nt < 4; nt++) {
                    ushort4 pv = *(const ushort4*)(SM + (mt * 4 + nt) * 1024 + partner * 4);
                    float part[4] = {bf2f(pv.x), bf2f(pv.y), bf2f(pv.z), bf2f(pv.w)};
                    int col = wn * 64 + nt * 16 + c;
#pragma unroll
                    for (int r = 0; r < 4; r++) {
                        int row = m0 + wm * 64 + mt * 16 + quad * 4 + r;
                        int b = row >> 11, s = row & 2047;
                        float cv = cosp[s * HD + col], sv = sinp[s * HD + col];
                        float out = (acc[mt][nt][r] * cv + sgn * part[r] * sv) * scl;
                        Cb[((size_t)(b * NH + h) * S_LEN + s) * HD + col] = f2bf(out);
                    }
                }
            }
        }
    }
}

// ---------------- flash attention (no-max online softmax, S^T formulation) ----------------
#define PKS 72  // P row stride in shorts (144B = 9*16: b128-aligned, conflict-free)
__global__ __launch_bounds__(256, 2) void attn_kernel(const unsigned short* __restrict__ Q,
                                                      const unsigned short* __restrict__ Kg,
                                                      const unsigned short* __restrict__ Vt,
                                                      unsigned short* __restrict__ Aout) {
    __shared__ unsigned short Ksm[64 * 128];            // 16 KB, [key][d], XOR-swizzled chunks
    __shared__ unsigned short Vsm[128 * 64];            // 16 KB, [d][key], XOR-swizzled chunks
    __shared__ __align__(16) unsigned short Psm[4 * 2 * 16 * PKS];  // 18 KB
    int bh = blockIdx.y;
    int b = bh >> 4, h = bh & 15;
    int t = threadIdx.x;
    int wave = t >> 6, lane = t & 63;
    int c = lane & 15, quad = lane >> 4;
    int q0 = blockIdx.x * 128 + wave * 32;
    const unsigned short* Qp = Q + (size_t)bh * S_LEN * HD;
    const unsigned short* Kp = Kg + (size_t)bh * S_LEN * HD;
    const unsigned short* Vp = Vt + (size_t)bh * HD * S_LEN;

    bf16x8 qf[2][4];
#pragma unroll
    for (int qn = 0; qn < 2; qn++)
#pragma unroll
        for (int kk = 0; kk < 4; kk++)
            qf[qn][kk] = *(const bf16x8*)(Qp + (size_t)(q0 + qn * 16 + c) * HD + kk * 32 + quad * 8);

    f32x4 zero = {0.f, 0.f, 0.f, 0.f};
    f32x4 o_acc[2][8];
#pragma unroll
    for (int qn = 0; qn < 2; qn++)
#pragma unroll
        for (int nt = 0; nt < 8; nt++) o_acc[qn][nt] = zero;
    float lsum[2] = {0.f, 0.f};

    for (int key0 = 0; key0 < S_LEN; key0 += 64) {
#pragma unroll
        for (int j = 0; j < 4; j++) {
            int fc = (wave * 4 + j) * 64 + lane;
            int rK = fc >> 4, cbK = (fc & 15) ^ (rK & 15);
            async16(Kp + (size_t)(key0 + rK) * HD + cbK * 8, Ksm + (wave * 4 + j) * 512);
            int rV = fc >> 3, cbV = (fc & 7) ^ (rV & 7);
            async16(Vp + (size_t)rV * S_LEN + key0 + cbV * 8, Vsm + (wave * 4 + j) * 512);
        }
        __syncthreads();

        f32x4 sacc[4][2];
#pragma unroll
        for (int km = 0; km < 4; km++)
#pragma unroll
            for (int qn = 0; qn < 2; qn++) sacc[km][qn] = zero;
#pragma unroll
        for (int kk = 0; kk < 4; kk++) {
            bf16x8 kfr[4];
#pragma unroll
            for (int km = 0; km < 4; km++)
                kfr[km] = *(const bf16x8*)(Ksm + (km * 16 + c) * HD + (((kk * 4 + quad) ^ c)) * 8);
#pragma unroll
            for (int km = 0; km < 4; km++)
#pragma unroll
                for (int qn = 0; qn < 2; qn++)
                    sacc[km][qn] = __builtin_amdgcn_mfma_f32_16x16x32_bf16(kfr[km], qf[qn][kk],
                                                                           sacc[km][qn], 0, 0, 0);
        }

#pragma unroll
        for (int qn = 0; qn < 2; qn++) {
#pragma unroll
            for (int km = 0; km < 4; km++) {
                float e0 = exp2_fast(sacc[km][qn][0]);
                float e1 = exp2_fast(sacc[km][qn][1]);
                float e2 = exp2_fast(sacc[km][qn][2]);
                float e3 = exp2_fast(sacc[km][qn][3]);
                lsum[qn] += (e0 + e1) + (e2 + e3);
                uint2 pk;
                pk.x = pkbf(e0, e1);
                pk.y = pkbf(e2, e3);
                *(uint2*)(Psm + ((wave * 2 + qn) * 16 + c) * PKS + km * 16 + quad * 4) = pk;
            }
        }
        asm volatile("" ::: "memory");
        __builtin_amdgcn_s_waitcnt(0xc07f);  // lgkmcnt(0), vmcnt/expcnt unaffected
        asm volatile("" ::: "memory");

#pragma unroll
        for (int kf = 0; kf < 2; kf++) {
            bf16x8 pf[2];
#pragma unroll
            for (int qn = 0; qn < 2; qn++)
                pf[qn] = *(const bf16x8*)(Psm + ((wave * 2 + qn) * 16 + c) * PKS + kf * 32 + quad * 8);
#pragma unroll
            for (int nt = 0; nt < 8; nt++) {
                bf16x8 vf = *(const bf16x8*)(Vsm + (nt * 16 + c) * 64 +
                                             (((kf * 4 + quad) ^ (c & 7))) * 8);
#pragma unroll
                for (int qn = 0; qn < 2; qn++)
                    o_acc[qn][nt] = __builtin_amdgcn_mfma_f32_16x16x32_bf16(pf[qn], vf,
                                                                            o_acc[qn][nt], 0, 0, 0);
            }
        }
        __syncthreads();
    }

#pragma unroll
    for (int qn = 0; qn < 2; qn++) {
        lsum[qn] += __shfl_xor(lsum[qn], 16);
        lsum[qn] += __shfl_xor(lsum[qn], 32);
    }
    float inv[2][4];
#pragma unroll
    for (int qn = 0; qn < 2; qn++)
#pragma unroll
        for (int r = 0; r < 4; r++)
            inv[qn][r] = 1.0f / __shfl(lsum[qn], quad * 4 + r);

#pragma unroll
    for (int qn = 0; qn < 2; qn++) {
#pragma unroll
        for (int r = 0; r < 4; r++) {
            int srow = q0 + qn * 16 + quad * 4 + r;
            size_t base = ((size_t)(b * S_LEN + srow)) * HID + h * HD;
#pragma unroll
            for (int nt = 0; nt < 8; nt++)
                Aout[base + nt * 16 + c] = f2bf(o_acc[qn][nt][r] * inv[qn][r]);
        }
    }
}

extern "C" void kernel_launch(void* const* d_in, const int* in_sizes, int n_in,
                              void* d_out, int out_size, void* d_ws, size_t ws_size,
                              hipStream_t stream) {
    const float* hs   = (const float*)d_in[0];
    const float* cosp = (const float*)d_in[1];
    const float* sinp = (const float*)d_in[2];
    const float* Wq   = (const float*)d_in[3];
    const float* Wk   = (const float*)d_in[4];
    const float* Wv   = (const float*)d_in[5];
    const float* Wo   = (const float*)d_in[6];

    char* ws = (char*)d_ws;
    unsigned short* Xb = (unsigned short*)(ws);                      // 0-16 MB (reused as Aout)
    unsigned short* Qb = (unsigned short*)(ws + (16ull << 20));      // 16-32
    unsigned short* Kb = (unsigned short*)(ws + (32ull << 20));      // 32-48
    unsigned short* Vb = (unsigned short*)(ws + (48ull << 20));      // 48-64
    unsigned short* WT = (unsigned short*)(ws + (64ull << 20));      // 64-88 fused / 64-72 single

    const bool fused = ws_size >= (88ull << 20);

    if (fused) {
        // 1. cast + 3 weight transposes in one launch
        prep<<<dim3(64, 64, 4), 256, 0, stream>>>(hs, Wq, Wk, Wv, Xb, WT);
        // 2. fused QKV GEMM (128x384 tile, reg-dbuf pipeline) + RoPE epilogue
        gemm_qkv<<<dim3(512), 512, 0, stream>>>(Xb, WT, Qb, Kb, Vb, cosp, sinp);
        // 3. flash attention
        attn_kernel<<<dim3(16, 32), 256, 0, stream>>>(Qb, Kb, Vb, Xb /*Aout*/);
        // 4. Wo transpose into dead Qb region
        unsigned short* WoT = (unsigned short*)(ws + (16ull << 20));
        transpose_cast<<<dim3(64, 64), 256, 0, stream>>>(Wo, WoT);
        // 5. output GEMM, fp32 direct to d_out
        gemm_bt<2><<<dim3(16, 32), 256, 0, stream>>>(Xb, WoT, nullptr, nullptr, nullptr,
                                                     (float*)d_out, cosp, sinp, 0);
    } else {
        prep<<<dim3(64, 64, 1), 256, 0, stream>>>(hs, Wq, Wq, Wq, Xb, WT);
        prep<<<dim3(64, 64, 4), 256, 0, stream>>>(hs, Wq, Wq, Wq, Xb, WT);  // cast + Wq^T
        gemm_bt<0><<<dim3(16, 32), 256, 0, stream>>>(Xb, WT, Qb, Kb, Vb, nullptr,
                                                     cosp, sinp, 0);
        transpose_cast<<<dim3(64, 64), 256, 0, stream>>>(Wk, WT);
        gemm_bt<0><<<dim3(16, 32), 256, 0, stream>>>(Xb, WT, Qb, Kb, Vb, nullptr,
                                                     cosp, sinp, 2048);
        transpose_cast<<<dim3(64, 64), 256, 0, stream>>>(Wv, WT);
        gemm_bt<0><<<dim3(16, 32), 256, 0, stream>>>(Xb, WT, Qb, Kb, Vb, nullptr,
                                                     cosp, sinp, 4096);
        attn_kernel<<<dim3(16, 32), 256, 0, stream>>>(Qb, Kb, Vb, Xb /*Aout*/);
        transpose_cast<<<dim3(64, 64), 256, 0, stream>>>(Wo, WT);
        gemm_bt<2><<<dim3(16, 32), 256, 0, stream>>>(Xb, WT, nullptr, nullptr, nullptr,
                                                     (float*)d_out, cosp, sinp, 0);
    }
}